// Round 13
// baseline (195.406 us; speedup 1.0000x reference)
//
#include <hip/hip_runtime.h>
#include <stdint.h>

#define BB   8
#define NN   8192
#define SSZ  2048
#define DD1  64
#define DD2  256
#define CINC 320
#define RTOT (BB*NN)   // 65536

typedef __attribute__((ext_vector_type(8))) __bf16 bf16x8;
typedef __attribute__((ext_vector_type(4))) __bf16 bf16x4;
typedef __attribute__((ext_vector_type(4))) float  f32x4;
typedef __attribute__((ext_vector_type(2))) float  f32x2;

__device__ __forceinline__ void gload_lds16(const void* g, void* l) {
    __builtin_amdgcn_global_load_lds((__attribute__((address_space(1))) void*)g,
                                     (__attribute__((address_space(3))) void*)l,
                                     16, 0, 0);
}

// median-of-3: guaranteed single v_med3_f32
__device__ __forceinline__ float med3f(float a, float b, float c) {
    float r;
    asm("v_med3_f32 %0, %1, %2, %3" : "=v"(r) : "v"(a), "v"(b), "v"(c));
    return r;
}

// ---------- K0: convert weights to bf16 ----------
__global__ void k_convert_w(const float* __restrict__ w0, const float* __restrict__ w1,
                            __bf16* __restrict__ wb0, __bf16* __restrict__ wb1) {
    int t = blockIdx.x * 256 + threadIdx.x;
    if (t < 256*CINC) wb0[t] = (__bf16)w0[t];
    if (t < 256*256)  wb1[t] = (__bf16)w1[t];
}

// ---------- K0b: pack xyz2 pairs -> [x0,x1,y0,y1][z0,z1,n0,n1] ----------
// Pair-SoA: one float4 load yields two ready-made VGPR pairs for v_pk_fma_f32.
__global__ void k_prep_xyz2(const float* __restrict__ xyz2, float4* __restrict__ o) {
    int b = blockIdx.y;
    int k = blockIdx.x * 256 + threadIdx.x;     // pair index 0..1023
    const float* x2 = xyz2 + (size_t)b*3*SSZ;
    int s0 = 2*k, s1 = 2*k+1;
    float xa = x2[s0],      xb = x2[s1];
    float ya = x2[SSZ+s0],  yb = x2[SSZ+s1];
    float za = x2[2*SSZ+s0],zb = x2[2*SSZ+s1];
    float na = fmaf(xa,xa,fmaf(ya,ya,za*za));
    float nb = fmaf(xb,xb,fmaf(yb,yb,zb*zb));
    size_t base = (size_t)b*SSZ + 2*k;          // 2 float4 per pair
    o[base+0] = make_float4(xa, xb, ya, yb);
    o[base+1] = make_float4(za, zb, na, nb);
}

// ---------- K1: transpose points2 (B,256,S) -> p2t (B,S,256) ----------
__global__ void k_transpose_p2(const float* __restrict__ p2, float* __restrict__ p2t) {
    __shared__ float tile[32][33];
    int b  = blockIdx.z;
    int s0 = blockIdx.x * 32;
    int c0 = blockIdx.y * 32;
    int tx = threadIdx.x & 31;
    int ty = threadIdx.x >> 5;       // 0..7
    const float* src = p2 + ((size_t)b*DD2 + c0)*SSZ + s0;
    for (int i = 0; i < 32; i += 8)
        tile[ty+i][tx] = src[(size_t)(ty+i)*SSZ + tx];        // [c][s]
    __syncthreads();
    float* dst = p2t + ((size_t)b*SSZ + s0)*DD2 + c0;
    for (int i = 0; i < 32; i += 8)
        dst[(size_t)(ty+i)*DD2 + tx] = tile[tx][ty+i];        // [s][c]
}

// ---------- K2: 3-NN + inverse-distance weights ----------
// EXACT f32 compares; 2 candidates/iter via packed v_pk_fma_f32 (float2
// elementwise fma); two sequential inserts in ascending index order => tie
// semantics identical to jax.lax.top_k. Branchless insert w/ v_med3_f32.
__global__ __launch_bounds__(512) void k_knn3(const float* __restrict__ xyz1,
                                              const float4* __restrict__ cand,
                                              int* __restrict__ idxO,
                                              float* __restrict__ wgtO) {
    __shared__ float cd[64][25];       // stride 25 (odd): conflict-free merge
    __shared__ int   ci[64][25];
    const int b  = blockIdx.y;
    const int n0 = blockIdx.x * 64;
    const int t  = threadIdx.x;
    const int nl = t & 63;
    const int chunk = __builtin_amdgcn_readfirstlane(t >> 6);  // wave-uniform 0..7
    const int n = n0 + nl;
    const float px = xyz1[(size_t)b*3*NN + n];
    const float py = xyz1[(size_t)b*3*NN + NN + n];
    const float pz = xyz1[(size_t)b*3*NN + 2*NN + n];
    const float ax = -2.f*px, ay = -2.f*py, az = -2.f*pz;
    const f32x2 ax2 = {ax, ax}, ay2 = {ay, ay}, az2 = {az, az};
    // key = |x2|^2 - 2 x1.x2  (|x1|^2 is a per-query constant; order-preserving)
    float t0=1e30f, t1=1e30f, t2=1e30f;
    int   i0=0, i1=0, i2=0;
    const int sbeg = chunk * 256;
    const float4* __restrict__ cb = cand + (size_t)b*SSZ + sbeg;  // 1 float4/cand
    #pragma unroll 8
    for (int s = 0; s < 256; s += 2) {
        float4 A = cb[s];       // x0,x1,y0,y1
        float4 Bv = cb[s+1];    // z0,z1,n0,n1
        f32x2 xs = {A.x, A.y}, ys = {A.z, A.w};
        f32x2 zs = {Bv.x, Bv.y}, ns = {Bv.z, Bv.w};
        f32x2 d2 = __builtin_elementwise_fma(ax2, xs,
                    __builtin_elementwise_fma(ay2, ys,
                     __builtin_elementwise_fma(az2, zs, ns)));
        {   // insert candidate sbeg+s (exact, strict '<')
            float d = d2.x; int sg = sbeg + s;
            bool b0 = d < t0, b1 = d < t1, b2 = d < t2;
            int ni0 = b0 ? sg : i0;
            int ni1 = b0 ? i0 : (b1 ? sg : i1);
            int ni2 = b1 ? i1 : (b2 ? sg : i2);
            float nt1 = med3f(t0, d, t1);
            float nt2 = med3f(t1, d, t2);
            t0 = fminf(t0, d);
            t1 = nt1; t2 = nt2;
            i0 = ni0; i1 = ni1; i2 = ni2;
        }
        {   // insert candidate sbeg+s+1
            float d = d2.y; int sg = sbeg + s + 1;
            bool b0 = d < t0, b1 = d < t1, b2 = d < t2;
            int ni0 = b0 ? sg : i0;
            int ni1 = b0 ? i0 : (b1 ? sg : i1);
            int ni2 = b1 ? i1 : (b2 ? sg : i2);
            float nt1 = med3f(t0, d, t1);
            float nt2 = med3f(t1, d, t2);
            t0 = fminf(t0, d);
            t1 = nt1; t2 = nt2;
            i0 = ni0; i1 = ni1; i2 = ni2;
        }
    }
    cd[nl][chunk*3+0]=t0; cd[nl][chunk*3+1]=t1; cd[nl][chunk*3+2]=t2;
    ci[nl][chunk*3+0]=i0; ci[nl][chunk*3+1]=i1; ci[nl][chunk*3+2]=i2;
    __syncthreads();
    if (t < 64) {
        float m0=1e30f, m1=1e30f, m2=1e30f;
        int   j0=0, j1=0, j2=0;
        #pragma unroll
        for (int k = 0; k < 24; ++k) {     // chunk-ascending order => stable ties
            float d = cd[t][k]; int si = ci[t][k];
            bool b0 = d < m0, b1 = d < m1, b2 = d < m2;
            int nj0 = b0 ? si : j0;
            int nj1 = b0 ? j0 : (b1 ? si : j1);
            int nj2 = b1 ? j1 : (b2 ? si : j2);
            float q1 = med3f(m0, d, m1);
            float q2 = med3f(m1, d, m2);
            m0 = fminf(m0, d);
            m1 = q1; m2 = q2;
            j0 = nj0; j1 = nj1; j2 = nj2;
        }
        const float q = fmaf(px,px,fmaf(py,py,pz*pz));
        float r0 = 1.f/((m0+q) + 1e-8f);
        float r1 = 1.f/((m1+q) + 1e-8f);
        float r2 = 1.f/((m2+q) + 1e-8f);
        float rs = 1.f/(r0+r1+r2);
        size_t o = ((size_t)b*NN + n0 + t)*3;
        idxO[o+0]=j0; idxO[o+1]=j1; idxO[o+2]=j2;
        wgtO[o+0]=r0*rs; wgtO[o+1]=r1*rs; wgtO[o+2]=r2*rs;
    }
}

// ---------- K3a: points1 (B,64,N) -> A1[:, 0:64] (bf16, row-major R x 320) ----------
__global__ void k_points1_to_A1(const float* __restrict__ p1, __bf16* __restrict__ A1) {
    __shared__ float tile[64][65];
    int b  = blockIdx.y;
    int n0 = blockIdx.x * 64;
    int t  = threadIdx.x;
    int tx = t & 63, ty = t >> 6;   // ty 0..3
    const float* src = p1 + (size_t)b*DD1*NN + n0;
    for (int i = 0; i < 64; i += 4)
        tile[ty+i][tx] = src[(size_t)(ty+i)*NN + tx];          // [c][n]
    __syncthreads();
    for (int i = 0; i < 64; i += 4) {
        int nl = ty + i;
        A1[((size_t)b*NN + n0 + nl)*CINC + tx] = (__bf16)tile[tx][nl];
    }
}

// ---------- K3b: gather+interp -> A1[:, 64:320] ----------
__global__ void k_interp(const float* __restrict__ p2t, const int* __restrict__ idx,
                         const float* __restrict__ wgt, __bf16* __restrict__ A1) {
    int b  = blockIdx.y;
    int n0 = blockIdx.x * 32;
    int c  = threadIdx.x;       // 0..255
    const float* pb = p2t + (size_t)b*SSZ*DD2;
    for (int r = 0; r < 32; ++r) {
        size_t nn = (size_t)b*NN + n0 + r;
        int   i0 = idx[nn*3+0], i1 = idx[nn*3+1], i2 = idx[nn*3+2];
        float w0 = wgt[nn*3+0], w1 = wgt[nn*3+1], w2 = wgt[nn*3+2];
        float v = w0*pb[(size_t)i0*DD2+c] + w1*pb[(size_t)i1*DD2+c] + w2*pb[(size_t)i2*DD2+c];
        A1[nn*CINC + DD1 + c] = (__bf16)v;
    }
}

// ---------- K4: bf16 MFMA GEMM1, Y = A(Rx320) * W(256x320)^T, + BN partial stats ----------
// 1-D grid with XCD-pair swizzle (kept: cheap, never hurts).
template<int KDIM>
__global__ __launch_bounds__(256) void k_gemm_bn(const __bf16* __restrict__ A,
                                                 const __bf16* __restrict__ W,
                                                 __bf16* __restrict__ Y,
                                                 float* __restrict__ psum,
                                                 float* __restrict__ psq) {
    __shared__ __bf16 As[128*64];
    __shared__ __bf16 Ws[128*64];
    __shared__ float  ssum[128];
    __shared__ float  ssq[128];
    const int t   = threadIdx.x;
    const int w   = t >> 6;
    const int l   = t & 63;
    const int bid = blockIdx.x;                 // 0..1023
    const int xcd = bid & 7;
    const int sub = (bid >> 3) & 1;             // nc half
    const int grp = bid >> 4;                   // 0..63
    const int mblk = grp * 8 + xcd;             // 0..511 (bijective)
    const int m0  = mblk * 128;
    const int nc0 = sub * 128;
    f32x4 acc[4][4] = {};
    const int rstage = t >> 3;          // 0..31
    const int cstage = (t & 7) * 8;     // element offset within K-slice
    for (int ks = 0; ks < KDIM/64; ++ks) {
        const int k0 = ks * 64;
        if (ks) __syncthreads();
        #pragma unroll
        for (int i = 0; i < 4; ++i) {
            const int row = i*32 + rstage;
            gload_lds16(A + (size_t)(m0 + row)*KDIM + k0 + cstage, As + row*64 + cstage);
            gload_lds16(W + (size_t)(nc0 + row)*KDIM + k0 + cstage, Ws + row*64 + cstage);
        }
        __syncthreads();   // drains vmcnt before barrier (compiler-inserted)
        const int wm = w >> 1, wn = w & 1;
        const int lr = l & 15, lk = (l >> 4) * 8;
        #pragma unroll
        for (int kk = 0; kk < 2; ++kk) {
            bf16x8 af[4], bw[4];
            #pragma unroll
            for (int mi = 0; mi < 4; ++mi)
                af[mi] = *(const bf16x8*)(As + (wm*64 + mi*16 + lr)*64 + kk*32 + lk);
            #pragma unroll
            for (int ni = 0; ni < 4; ++ni)
                bw[ni] = *(const bf16x8*)(Ws + (wn*64 + ni*16 + lr)*64 + kk*32 + lk);
            #pragma unroll
            for (int mi = 0; mi < 4; ++mi)
                #pragma unroll
                for (int ni = 0; ni < 4; ++ni)
                    acc[mi][ni] = __builtin_amdgcn_mfma_f32_16x16x32_bf16(af[mi], bw[ni], acc[mi][ni], 0, 0, 0);
        }
    }
    if (t < 128) { ssum[t] = 0.f; ssq[t] = 0.f; }
    __syncthreads();
    const int wm = w >> 1, wn = w & 1;
    const int lr = l & 15, lg = l >> 4;
    #pragma unroll
    for (int ni = 0; ni < 4; ++ni) {
        const int cl = wn*64 + ni*16 + lr;
        float lsum = 0.f, lsq = 0.f;
        #pragma unroll
        for (int mi = 0; mi < 4; ++mi) {
            #pragma unroll
            for (int v = 0; v < 4; ++v) {
                float val = acc[mi][ni][v];
                int row = m0 + wm*64 + mi*16 + lg*4 + v;
                Y[(size_t)row*256 + nc0 + cl] = (__bf16)val;
                lsum += val; lsq += val*val;
            }
        }
        atomicAdd(&ssum[cl], lsum);
        atomicAdd(&ssq[cl],  lsq);
    }
    __syncthreads();
    if (t < 128) {
        psum[(size_t)mblk*256 + nc0 + t] = ssum[t];
        psq [(size_t)mblk*256 + nc0 + t] = ssq[t];
    }
}

// ---------- K6: GEMM2 with fused BN1+ReLU on the A path ----------
__global__ __launch_bounds__(256) void k_gemm2_fused(const __bf16* __restrict__ Yin,
                                                     const float* __restrict__ coef,
                                                     const __bf16* __restrict__ W,
                                                     __bf16* __restrict__ Y,
                                                     float* __restrict__ psum,
                                                     float* __restrict__ psq) {
    __shared__ __bf16 As[128*64];
    __shared__ __bf16 Ws[128*64];
    __shared__ float  ssum[128];
    __shared__ float  ssq[128];
    const int t   = threadIdx.x;
    const int w   = t >> 6;
    const int l   = t & 63;
    const int bid = blockIdx.x;
    const int xcd = bid & 7;
    const int sub = (bid >> 3) & 1;
    const int grp = bid >> 4;
    const int mblk = grp * 8 + xcd;
    const int m0  = mblk * 128;
    const int nc0 = sub * 128;
    f32x4 acc[4][4] = {};
    const int rstage = t >> 3;          // 0..31
    const int cstage = (t & 7) * 8;     // channel offset within K-slice
    for (int ks = 0; ks < 4; ++ks) {
        const int k0 = ks * 64;
        f32x4 sc0 = *(const f32x4*)(coef + k0 + cstage);
        f32x4 sc1 = *(const f32x4*)(coef + k0 + cstage + 4);
        f32x4 sh0 = *(const f32x4*)(coef + 256 + k0 + cstage);
        f32x4 sh1 = *(const f32x4*)(coef + 256 + k0 + cstage + 4);
        if (ks) __syncthreads();
        #pragma unroll
        for (int i = 0; i < 4; ++i) {
            const int row = i*32 + rstage;
            bf16x8 v = *(const bf16x8*)(Yin + (size_t)(m0 + row)*256 + k0 + cstage);
            bf16x8 r;
            #pragma unroll
            for (int j = 0; j < 4; ++j) {
                r[j]   = (__bf16)fmaxf(fmaf(sc0[j], (float)v[j],   sh0[j]), 0.f);
                r[j+4] = (__bf16)fmaxf(fmaf(sc1[j], (float)v[j+4], sh1[j]), 0.f);
            }
            *(bf16x8*)(As + row*64 + cstage) = r;
            gload_lds16(W + (size_t)(nc0 + row)*256 + k0 + cstage, Ws + row*64 + cstage);
        }
        __syncthreads();
        const int wm = w >> 1, wn = w & 1;
        const int lr = l & 15, lk = (l >> 4) * 8;
        #pragma unroll
        for (int kk = 0; kk < 2; ++kk) {
            bf16x8 af[4], bw[4];
            #pragma unroll
            for (int mi = 0; mi < 4; ++mi)
                af[mi] = *(const bf16x8*)(As + (wm*64 + mi*16 + lr)*64 + kk*32 + lk);
            #pragma unroll
            for (int ni = 0; ni < 4; ++ni)
                bw[ni] = *(const bf16x8*)(Ws + (wn*64 + ni*16 + lr)*64 + kk*32 + lk);
            #pragma unroll
            for (int mi = 0; mi < 4; ++mi)
                #pragma unroll
                for (int ni = 0; ni < 4; ++ni)
                    acc[mi][ni] = __builtin_amdgcn_mfma_f32_16x16x32_bf16(af[mi], bw[ni], acc[mi][ni], 0, 0, 0);
        }
    }
    if (t < 128) { ssum[t] = 0.f; ssq[t] = 0.f; }
    __syncthreads();
    const int wm = w >> 1, wn = w & 1;
    const int lr = l & 15, lg = l >> 4;
    #pragma unroll
    for (int ni = 0; ni < 4; ++ni) {
        const int cl = wn*64 + ni*16 + lr;
        float lsum = 0.f, lsq = 0.f;
        #pragma unroll
        for (int mi = 0; mi < 4; ++mi) {
            #pragma unroll
            for (int v = 0; v < 4; ++v) {
                float val = acc[mi][ni][v];
                int row = m0 + wm*64 + mi*16 + lg*4 + v;
                Y[(size_t)row*256 + nc0 + cl] = (__bf16)val;
                lsum += val; lsq += val*val;
            }
        }
        atomicAdd(&ssum[cl], lsum);
        atomicAdd(&ssq[cl],  lsq);
    }
    __syncthreads();
    if (t < 128) {
        psum[(size_t)mblk*256 + nc0 + t] = ssum[t];
        psq [(size_t)mblk*256 + nc0 + t] = ssq[t];
    }
}

// ---------- K5a: stage-1 BN reduce — 64 blocks x 8 rows, coalesced ----------
__global__ void k_bnpart(const float* __restrict__ psum, const float* __restrict__ psq,
                         float* __restrict__ partS, float* __restrict__ partQ) {
    int i = blockIdx.x;          // 0..63
    int c = threadIdx.x;         // 0..255
    float s = 0.f, q = 0.f;
    #pragma unroll
    for (int r = 0; r < 8; ++r) {
        s += psum[(size_t)(i*8+r)*256 + c];
        q += psq [(size_t)(i*8+r)*256 + c];
    }
    partS[(size_t)i*256 + c] = s;
    partQ[(size_t)i*256 + c] = q;
}

// ---------- K5b: stage-2 -> (scale, shift) per channel ----------
// Fixed-order fold (deterministic). Conv biases b0/b1 cancel under BN mean-sub.
__global__ void k_bnstat(const float* __restrict__ partS, const float* __restrict__ partQ,
                         const float* __restrict__ g, const float* __restrict__ be,
                         float* __restrict__ coef) {
    int c = threadIdx.x;    // 256
    float s = 0.f, q = 0.f;
    #pragma unroll 8
    for (int i = 0; i < 64; ++i) {
        s += partS[(size_t)i*256 + c];
        q += partQ[(size_t)i*256 + c];
    }
    float mean = s * (1.f/RTOT);
    float var  = q * (1.f/RTOT) - mean*mean;
    float sc = g[c] * rsqrtf(var + 1e-5f);
    coef[c]       = sc;
    coef[256 + c] = be[c] - mean * sc;
}

// ---------- K8: out[b][c][n] = relu(scale2*y2 + shift2), transposed store ----------
__global__ void k_final(const __bf16* __restrict__ y, const float* __restrict__ coef,
                        float* __restrict__ out) {
    __shared__ float tile[64][65];
    int b  = blockIdx.z;
    int n0 = blockIdx.x * 64;
    int c0 = blockIdx.y * 64;
    int t  = threadIdx.x;
    int c4 = (t & 15) * 4;
    int nr = t >> 4;                    // 0..15
    for (int i = 0; i < 64; i += 16) {
        int nl = nr + i;
        const __bf16* src = y + ((size_t)b*NN + n0 + nl)*256 + c0 + c4;
        bf16x4 v = *(const bf16x4*)src;
        #pragma unroll
        for (int j = 0; j < 4; ++j) {
            int c = c0 + c4 + j;
            float f = fmaf(coef[c], (float)v[j], coef[256+c]);
            tile[nl][c4+j] = fmaxf(f, 0.f);
        }
    }
    __syncthreads();
    int n4 = (t & 15) * 4;
    int cr = t >> 4;
    for (int i = 0; i < 64; i += 16) {
        int cl = cr + i;
        float4 o;
        o.x = tile[n4+0][cl]; o.y = tile[n4+1][cl];
        o.z = tile[n4+2][cl]; o.w = tile[n4+3][cl];
        *(float4*)(out + ((size_t)b*256 + c0 + cl)*NN + n0 + n4) = o;
    }
}

extern "C" void kernel_launch(void* const* d_in, const int* in_sizes, int n_in,
                              void* d_out, int out_size, void* d_ws, size_t ws_size,
                              hipStream_t stream) {
    (void)in_sizes; (void)n_in; (void)out_size; (void)ws_size;
    const float* xyz1    = (const float*)d_in[0];
    const float* xyz2    = (const float*)d_in[1];
    const float* points1 = (const float*)d_in[2];
    const float* points2 = (const float*)d_in[3];
    const float* w0      = (const float*)d_in[4];
    // d_in[5] = b0 (cancels under BN), d_in[9] = b1 (cancels)
    const float* g0      = (const float*)d_in[6];
    const float* be0     = (const float*)d_in[7];
    const float* w1      = (const float*)d_in[8];
    const float* g1      = (const float*)d_in[10];
    const float* be1     = (const float*)d_in[11];
    float* out = (float*)d_out;

    char* p = (char*)d_ws;
    float* p2t  = (float*)p;   p += (size_t)BB*SSZ*DD2*4;       // 16 MB
    int*   idx  = (int*)p;     p += (size_t)RTOT*3*4;
    float* wgt  = (float*)p;   p += (size_t)RTOT*3*4;
    __bf16* A1  = (__bf16*)p;  p += (size_t)RTOT*CINC*2;        // 40 MB
    __bf16* y1  = (__bf16*)p;  p += (size_t)RTOT*256*2;         // 32 MB
    __bf16* wb0 = (__bf16*)p;  p += (size_t)256*CINC*2;
    __bf16* wb1 = (__bf16*)p;  p += (size_t)256*256*2;
    float* psum1 = (float*)p;  p += (size_t)(RTOT/128)*256*4;
    float* psq1  = (float*)p;  p += (size_t)(RTOT/128)*256*4;
    float* psum2 = (float*)p;  p += (size_t)(RTOT/128)*256*4;
    float* psq2  = (float*)p;  p += (size_t)(RTOT/128)*256*4;
    float* coef1 = (float*)p;  p += 512*4;
    float* coef2 = (float*)p;  p += 512*4;
    float4* xyz2f4 = (float4*)p; p += (size_t)BB*SSZ*16;        // 256 KB
    float* partS = (float*)p;  p += (size_t)64*256*4;           // 64 KB
    float* partQ = (float*)p;  p += (size_t)64*256*4;           // 64 KB
    __bf16* y2 = A1;   // A1 dead after GEMM1 -> reuse for y2 (32 MB < 40 MB)

    k_prep_xyz2   <<<dim3(SSZ/512, BB),         dim3(256), 0, stream>>>(xyz2, xyz2f4);
    k_convert_w   <<<dim3(320),                 dim3(256), 0, stream>>>(w0, w1, wb0, wb1);
    k_transpose_p2<<<dim3(SSZ/32, DD2/32, BB),  dim3(256), 0, stream>>>(points2, p2t);
    k_knn3        <<<dim3(NN/64, BB),           dim3(512), 0, stream>>>(xyz1, xyz2f4, idx, wgt);
    k_points1_to_A1<<<dim3(NN/64, BB),          dim3(256), 0, stream>>>(points1, A1);
    k_interp      <<<dim3(NN/32, BB),           dim3(256), 0, stream>>>(p2t, idx, wgt, A1);
    k_gemm_bn<CINC><<<dim3(RTOT/64),            dim3(256), 0, stream>>>(A1, wb0, y1, psum1, psq1);
    k_bnpart      <<<dim3(64),                  dim3(256), 0, stream>>>(psum1, psq1, partS, partQ);
    k_bnstat      <<<dim3(1),                   dim3(256), 0, stream>>>(partS, partQ, g0, be0, coef1);
    k_gemm2_fused <<<dim3(RTOT/64),             dim3(256), 0, stream>>>(y1, coef1, wb1, y2, psum2, psq2);
    k_bnpart      <<<dim3(64),                  dim3(256), 0, stream>>>(psum2, psq2, partS, partQ);
    k_bnstat      <<<dim3(1),                   dim3(256), 0, stream>>>(partS, partQ, g1, be1, coef2);
    k_final       <<<dim3(NN/64, 256/64, BB),   dim3(256), 0, stream>>>(y2, coef2, out);
}

// Round 14
// 190.452 us; speedup vs baseline: 1.0260x; 1.0260x over previous
//
#include <hip/hip_runtime.h>
#include <stdint.h>

#define BB   8
#define NN   8192
#define SSZ  2048
#define DD1  64
#define DD2  256
#define CINC 320
#define RTOT (BB*NN)   // 65536

typedef __attribute__((ext_vector_type(8))) __bf16 bf16x8;
typedef __attribute__((ext_vector_type(4))) __bf16 bf16x4;
typedef __attribute__((ext_vector_type(4))) float  f32x4;

__device__ __forceinline__ void gload_lds16(const void* g, void* l) {
    __builtin_amdgcn_global_load_lds((__attribute__((address_space(1))) void*)g,
                                     (__attribute__((address_space(3))) void*)l,
                                     16, 0, 0);
}

// median-of-3: guaranteed single v_med3_f32
__device__ __forceinline__ float med3f(float a, float b, float c) {
    float r;
    asm("v_med3_f32 %0, %1, %2, %3" : "=v"(r) : "v"(a), "v"(b), "v"(c));
    return r;
}

// ---------- K0: fused tiny prep — xyz2 pack | weight cvt (no LDS, no coupling) ----------
__global__ void k_prep0(const float* __restrict__ xyz2, float4* __restrict__ xyz2f4,
                        const float* __restrict__ w0, const float* __restrict__ w1,
                        __bf16* __restrict__ wb0, __bf16* __restrict__ wb1) {
    const int blk = blockIdx.x;
    const int t   = threadIdx.x;
    if (blk < 64) {                  // pack xyz2 -> (x,y,z,|p|^2)
        int b = blk >> 3, sb = blk & 7;
        int s = sb*256 + t;
        const float* x2 = xyz2 + (size_t)b*3*SSZ;
        float a = x2[s], c = x2[SSZ+s], d = x2[2*SSZ+s];
        xyz2f4[(size_t)b*SSZ + s] = make_float4(a, c, d, fmaf(a,a,fmaf(c,c,d*d)));
        return;
    }
    int i = (blk-64)*256 + t;        // weights -> bf16
    if (i < 256*CINC) wb0[i] = (__bf16)w0[i];
    if (i < 256*256)  wb1[i] = (__bf16)w1[i];
}

// ---------- K1: transpose points2 (B,256,S) -> p2t (B,S,256) ----------
__global__ void k_transpose_p2(const float* __restrict__ p2, float* __restrict__ p2t) {
    __shared__ float tile[32][33];
    int b  = blockIdx.z;
    int s0 = blockIdx.x * 32;
    int c0 = blockIdx.y * 32;
    int tx = threadIdx.x & 31;
    int ty = threadIdx.x >> 5;       // 0..7
    const float* src = p2 + ((size_t)b*DD2 + c0)*SSZ + s0;
    for (int i = 0; i < 32; i += 8)
        tile[ty+i][tx] = src[(size_t)(ty+i)*SSZ + tx];        // [c][s]
    __syncthreads();
    float* dst = p2t + ((size_t)b*SSZ + s0)*DD2 + c0;
    for (int i = 0; i < 32; i += 8)
        dst[(size_t)(ty+i)*DD2 + tx] = tile[tx][ty+i];        // [s][c]
}

// ---------- K2: 3-NN + inverse-distance weights (R11 config — parked best) ----------
// EXACT f32 compares; branchless top-3 with forced v_med3_f32; strict '<' +
// ascending index order => stable ties (matches jax.lax.top_k).
__global__ __launch_bounds__(512) void k_knn3(const float* __restrict__ xyz1,
                                              const float4* __restrict__ cand,
                                              int* __restrict__ idxO,
                                              float* __restrict__ wgtO) {
    __shared__ float cd[64][25];       // stride 25 (odd): conflict-free merge
    __shared__ int   ci[64][25];
    const int b  = blockIdx.y;
    const int n0 = blockIdx.x * 64;
    const int t  = threadIdx.x;
    const int nl = t & 63;
    const int chunk = __builtin_amdgcn_readfirstlane(t >> 6);  // wave-uniform 0..7
    const int n = n0 + nl;
    const float px = xyz1[(size_t)b*3*NN + n];
    const float py = xyz1[(size_t)b*3*NN + NN + n];
    const float pz = xyz1[(size_t)b*3*NN + 2*NN + n];
    const float ax = -2.f*px, ay = -2.f*py, az = -2.f*pz;
    // key = |x2|^2 - 2 x1.x2  (|x1|^2 is a per-query constant; order-preserving)
    float t0=1e30f, t1=1e30f, t2=1e30f;
    int   i0=0, i1=0, i2=0;
    const int sbeg = chunk * 256;
    const float4* __restrict__ cb = cand + (size_t)b*SSZ + sbeg;
    #pragma unroll 16
    for (int s = 0; s < 256; ++s) {
        float4 c = cb[s];                         // uniform address -> broadcast
        float d = fmaf(ax, c.x, fmaf(ay, c.y, fmaf(az, c.z, c.w)));
        int sg = sbeg + s;
        bool b0 = d < t0, b1 = d < t1, b2 = d < t2;
        int ni0 = b0 ? sg : i0;
        int ni1 = b0 ? i0 : (b1 ? sg : i1);
        int ni2 = b1 ? i1 : (b2 ? sg : i2);
        float nt1 = med3f(t0, d, t1);
        float nt2 = med3f(t1, d, t2);
        t0 = fminf(t0, d);
        t1 = nt1; t2 = nt2;
        i0 = ni0; i1 = ni1; i2 = ni2;
    }
    cd[nl][chunk*3+0]=t0; cd[nl][chunk*3+1]=t1; cd[nl][chunk*3+2]=t2;
    ci[nl][chunk*3+0]=i0; ci[nl][chunk*3+1]=i1; ci[nl][chunk*3+2]=i2;
    __syncthreads();
    if (t < 64) {
        float m0=1e30f, m1=1e30f, m2=1e30f;
        int   j0=0, j1=0, j2=0;
        #pragma unroll
        for (int k = 0; k < 24; ++k) {     // chunk-ascending order => stable ties
            float d = cd[t][k]; int si = ci[t][k];
            bool b0 = d < m0, b1 = d < m1, b2 = d < m2;
            int nj0 = b0 ? si : j0;
            int nj1 = b0 ? j0 : (b1 ? si : j1);
            int nj2 = b1 ? j1 : (b2 ? si : j2);
            float q1 = med3f(m0, d, m1);
            float q2 = med3f(m1, d, m2);
            m0 = fminf(m0, d);
            m1 = q1; m2 = q2;
            j0 = nj0; j1 = nj1; j2 = nj2;
        }
        const float q = fmaf(px,px,fmaf(py,py,pz*pz));
        float r0 = 1.f/((m0+q) + 1e-8f);
        float r1 = 1.f/((m1+q) + 1e-8f);
        float r2 = 1.f/((m2+q) + 1e-8f);
        float rs = 1.f/(r0+r1+r2);
        size_t o = ((size_t)b*NN + n0 + t)*3;
        idxO[o+0]=j0; idxO[o+1]=j1; idxO[o+2]=j2;
        wgtO[o+0]=r0*rs; wgtO[o+1]=r1*rs; wgtO[o+2]=r2*rs;
    }
}

// ---------- K3a: points1 (B,64,N) -> A1[:, 0:64] (bf16, row-major R x 320) ----------
__global__ void k_points1_to_A1(const float* __restrict__ p1, __bf16* __restrict__ A1) {
    __shared__ float tile[64][65];
    int b  = blockIdx.y;
    int n0 = blockIdx.x * 64;
    int t  = threadIdx.x;
    int tx = t & 63, ty = t >> 6;   // ty 0..3
    const float* src = p1 + (size_t)b*DD1*NN + n0;
    for (int i = 0; i < 64; i += 4)
        tile[ty+i][tx] = src[(size_t)(ty+i)*NN + tx];          // [c][n]
    __syncthreads();
    for (int i = 0; i < 64; i += 4) {
        int nl = ty + i;
        A1[((size_t)b*NN + n0 + nl)*CINC + tx] = (__bf16)tile[tx][nl];
    }
}

// ---------- K3b: gather+interp -> A1[:, 64:320] ----------
__global__ void k_interp(const float* __restrict__ p2t, const int* __restrict__ idx,
                         const float* __restrict__ wgt, __bf16* __restrict__ A1) {
    int b  = blockIdx.y;
    int n0 = blockIdx.x * 32;
    int c  = threadIdx.x;       // 0..255
    const float* pb = p2t + (size_t)b*SSZ*DD2;
    for (int r = 0; r < 32; ++r) {
        size_t nn = (size_t)b*NN + n0 + r;
        int   i0 = idx[nn*3+0], i1 = idx[nn*3+1], i2 = idx[nn*3+2];
        float w0 = wgt[nn*3+0], w1 = wgt[nn*3+1], w2 = wgt[nn*3+2];
        float v = w0*pb[(size_t)i0*DD2+c] + w1*pb[(size_t)i1*DD2+c] + w2*pb[(size_t)i2*DD2+c];
        A1[nn*CINC + DD1 + c] = (__bf16)v;
    }
}

// ---------- K4: bf16 MFMA GEMM1, Y = A(Rx320) * W(256x320)^T, + BN partial stats ----------
// 1-D grid with XCD-pair swizzle (kept: cheap, never hurts).
template<int KDIM>
__global__ __launch_bounds__(256) void k_gemm_bn(const __bf16* __restrict__ A,
                                                 const __bf16* __restrict__ W,
                                                 __bf16* __restrict__ Y,
                                                 float* __restrict__ psum,
                                                 float* __restrict__ psq) {
    __shared__ __bf16 As[128*64];
    __shared__ __bf16 Ws[128*64];
    __shared__ float  ssum[128];
    __shared__ float  ssq[128];
    const int t   = threadIdx.x;
    const int w   = t >> 6;
    const int l   = t & 63;
    const int bid = blockIdx.x;                 // 0..1023
    const int xcd = bid & 7;
    const int sub = (bid >> 3) & 1;             // nc half
    const int grp = bid >> 4;                   // 0..63
    const int mblk = grp * 8 + xcd;             // 0..511 (bijective)
    const int m0  = mblk * 128;
    const int nc0 = sub * 128;
    f32x4 acc[4][4] = {};
    const int rstage = t >> 3;          // 0..31
    const int cstage = (t & 7) * 8;     // element offset within K-slice
    for (int ks = 0; ks < KDIM/64; ++ks) {
        const int k0 = ks * 64;
        if (ks) __syncthreads();
        #pragma unroll
        for (int i = 0; i < 4; ++i) {
            const int row = i*32 + rstage;
            gload_lds16(A + (size_t)(m0 + row)*KDIM + k0 + cstage, As + row*64 + cstage);
            gload_lds16(W + (size_t)(nc0 + row)*KDIM + k0 + cstage, Ws + row*64 + cstage);
        }
        __syncthreads();   // drains vmcnt before barrier (compiler-inserted)
        const int wm = w >> 1, wn = w & 1;
        const int lr = l & 15, lk = (l >> 4) * 8;
        #pragma unroll
        for (int kk = 0; kk < 2; ++kk) {
            bf16x8 af[4], bw[4];
            #pragma unroll
            for (int mi = 0; mi < 4; ++mi)
                af[mi] = *(const bf16x8*)(As + (wm*64 + mi*16 + lr)*64 + kk*32 + lk);
            #pragma unroll
            for (int ni = 0; ni < 4; ++ni)
                bw[ni] = *(const bf16x8*)(Ws + (wn*64 + ni*16 + lr)*64 + kk*32 + lk);
            #pragma unroll
            for (int mi = 0; mi < 4; ++mi)
                #pragma unroll
                for (int ni = 0; ni < 4; ++ni)
                    acc[mi][ni] = __builtin_amdgcn_mfma_f32_16x16x32_bf16(af[mi], bw[ni], acc[mi][ni], 0, 0, 0);
        }
    }
    if (t < 128) { ssum[t] = 0.f; ssq[t] = 0.f; }
    __syncthreads();
    const int wm = w >> 1, wn = w & 1;
    const int lr = l & 15, lg = l >> 4;
    #pragma unroll
    for (int ni = 0; ni < 4; ++ni) {
        const int cl = wn*64 + ni*16 + lr;
        float lsum = 0.f, lsq = 0.f;
        #pragma unroll
        for (int mi = 0; mi < 4; ++mi) {
            #pragma unroll
            for (int v = 0; v < 4; ++v) {
                float val = acc[mi][ni][v];
                int row = m0 + wm*64 + mi*16 + lg*4 + v;
                Y[(size_t)row*256 + nc0 + cl] = (__bf16)val;
                lsum += val; lsq += val*val;
            }
        }
        atomicAdd(&ssum[cl], lsum);
        atomicAdd(&ssq[cl],  lsq);
    }
    __syncthreads();
    if (t < 128) {
        psum[(size_t)mblk*256 + nc0 + t] = ssum[t];
        psq [(size_t)mblk*256 + nc0 + t] = ssq[t];
    }
}

// ---------- K6: GEMM2 with fused BN1+ReLU on the A path ----------
// Reads y1 directly; A2 = bf16(relu(scale*y1+shift)) computed in registers
// during staging (identical f32 math + bf16 rounding as the old k_bnrelu ->
// bit-identical MFMA inputs). W stays on global_load_lds.
__global__ __launch_bounds__(256) void k_gemm2_fused(const __bf16* __restrict__ Yin,
                                                     const float* __restrict__ coef,
                                                     const __bf16* __restrict__ W,
                                                     __bf16* __restrict__ Y,
                                                     float* __restrict__ psum,
                                                     float* __restrict__ psq) {
    __shared__ __bf16 As[128*64];
    __shared__ __bf16 Ws[128*64];
    __shared__ float  ssum[128];
    __shared__ float  ssq[128];
    const int t   = threadIdx.x;
    const int w   = t >> 6;
    const int l   = t & 63;
    const int bid = blockIdx.x;
    const int xcd = bid & 7;
    const int sub = (bid >> 3) & 1;
    const int grp = bid >> 4;
    const int mblk = grp * 8 + xcd;
    const int m0  = mblk * 128;
    const int nc0 = sub * 128;
    f32x4 acc[4][4] = {};
    const int rstage = t >> 3;          // 0..31
    const int cstage = (t & 7) * 8;     // channel offset within K-slice
    for (int ks = 0; ks < 4; ++ks) {
        const int k0 = ks * 64;
        f32x4 sc0 = *(const f32x4*)(coef + k0 + cstage);
        f32x4 sc1 = *(const f32x4*)(coef + k0 + cstage + 4);
        f32x4 sh0 = *(const f32x4*)(coef + 256 + k0 + cstage);
        f32x4 sh1 = *(const f32x4*)(coef + 256 + k0 + cstage + 4);
        if (ks) __syncthreads();
        #pragma unroll
        for (int i = 0; i < 4; ++i) {
            const int row = i*32 + rstage;
            bf16x8 v = *(const bf16x8*)(Yin + (size_t)(m0 + row)*256 + k0 + cstage);
            bf16x8 r;
            #pragma unroll
            for (int j = 0; j < 4; ++j) {
                r[j]   = (__bf16)fmaxf(fmaf(sc0[j], (float)v[j],   sh0[j]), 0.f);
                r[j+4] = (__bf16)fmaxf(fmaf(sc1[j], (float)v[j+4], sh1[j]), 0.f);
            }
            *(bf16x8*)(As + row*64 + cstage) = r;
            gload_lds16(W + (size_t)(nc0 + row)*256 + k0 + cstage, Ws + row*64 + cstage);
        }
        __syncthreads();
        const int wm = w >> 1, wn = w & 1;
        const int lr = l & 15, lk = (l >> 4) * 8;
        #pragma unroll
        for (int kk = 0; kk < 2; ++kk) {
            bf16x8 af[4], bw[4];
            #pragma unroll
            for (int mi = 0; mi < 4; ++mi)
                af[mi] = *(const bf16x8*)(As + (wm*64 + mi*16 + lr)*64 + kk*32 + lk);
            #pragma unroll
            for (int ni = 0; ni < 4; ++ni)
                bw[ni] = *(const bf16x8*)(Ws + (wn*64 + ni*16 + lr)*64 + kk*32 + lk);
            #pragma unroll
            for (int mi = 0; mi < 4; ++mi)
                #pragma unroll
                for (int ni = 0; ni < 4; ++ni)
                    acc[mi][ni] = __builtin_amdgcn_mfma_f32_16x16x32_bf16(af[mi], bw[ni], acc[mi][ni], 0, 0, 0);
        }
    }
    if (t < 128) { ssum[t] = 0.f; ssq[t] = 0.f; }
    __syncthreads();
    const int wm = w >> 1, wn = w & 1;
    const int lr = l & 15, lg = l >> 4;
    #pragma unroll
    for (int ni = 0; ni < 4; ++ni) {
        const int cl = wn*64 + ni*16 + lr;
        float lsum = 0.f, lsq = 0.f;
        #pragma unroll
        for (int mi = 0; mi < 4; ++mi) {
            #pragma unroll
            for (int v = 0; v < 4; ++v) {
                float val = acc[mi][ni][v];
                int row = m0 + wm*64 + mi*16 + lg*4 + v;
                Y[(size_t)row*256 + nc0 + cl] = (__bf16)val;
                lsum += val; lsq += val*val;
            }
        }
        atomicAdd(&ssum[cl], lsum);
        atomicAdd(&ssq[cl],  lsq);
    }
    __syncthreads();
    if (t < 128) {
        psum[(size_t)mblk*256 + nc0 + t] = ssum[t];
        psq [(size_t)mblk*256 + nc0 + t] = ssq[t];
    }
}

// ---------- K5a: stage-1 BN reduce — 64 blocks x 8 rows, coalesced ----------
__global__ void k_bnpart(const float* __restrict__ psum, const float* __restrict__ psq,
                         float* __restrict__ partS, float* __restrict__ partQ) {
    int i = blockIdx.x;          // 0..63
    int c = threadIdx.x;         // 0..255
    float s = 0.f, q = 0.f;
    #pragma unroll
    for (int r = 0; r < 8; ++r) {
        s += psum[(size_t)(i*8+r)*256 + c];
        q += psq [(size_t)(i*8+r)*256 + c];
    }
    partS[(size_t)i*256 + c] = s;
    partQ[(size_t)i*256 + c] = q;
}

// ---------- K5b: stage-2 -> (scale, shift) per channel ----------
// Fixed-order fold (deterministic). Conv biases b0/b1 cancel under BN mean-sub.
__global__ void k_bnstat(const float* __restrict__ partS, const float* __restrict__ partQ,
                         const float* __restrict__ g, const float* __restrict__ be,
                         float* __restrict__ coef) {
    int c = threadIdx.x;    // 256
    float s = 0.f, q = 0.f;
    #pragma unroll 8
    for (int i = 0; i < 64; ++i) {
        s += partS[(size_t)i*256 + c];
        q += partQ[(size_t)i*256 + c];
    }
    float mean = s * (1.f/RTOT);
    float var  = q * (1.f/RTOT) - mean*mean;
    float sc = g[c] * rsqrtf(var + 1e-5f);
    coef[c]       = sc;
    coef[256 + c] = be[c] - mean * sc;
}

// ---------- K8: out[b][c][n] = relu(scale2*y2 + shift2), transposed store ----------
__global__ void k_final(const __bf16* __restrict__ y, const float* __restrict__ coef,
                        float* __restrict__ out) {
    __shared__ float tile[64][65];
    int b  = blockIdx.z;
    int n0 = blockIdx.x * 64;
    int c0 = blockIdx.y * 64;
    int t  = threadIdx.x;
    int c4 = (t & 15) * 4;
    int nr = t >> 4;                    // 0..15
    for (int i = 0; i < 64; i += 16) {
        int nl = nr + i;
        const __bf16* src = y + ((size_t)b*NN + n0 + nl)*256 + c0 + c4;
        bf16x4 v = *(const bf16x4*)src;
        #pragma unroll
        for (int j = 0; j < 4; ++j) {
            int c = c0 + c4 + j;
            float f = fmaf(coef[c], (float)v[j], coef[256+c]);
            tile[nl][c4+j] = fmaxf(f, 0.f);
        }
    }
    __syncthreads();
    int n4 = (t & 15) * 4;
    int cr = t >> 4;
    for (int i = 0; i < 64; i += 16) {
        int cl = cr + i;
        float4 o;
        o.x = tile[n4+0][cl]; o.y = tile[n4+1][cl];
        o.z = tile[n4+2][cl]; o.w = tile[n4+3][cl];
        *(float4*)(out + ((size_t)b*256 + c0 + cl)*NN + n0 + n4) = o;
    }
}

extern "C" void kernel_launch(void* const* d_in, const int* in_sizes, int n_in,
                              void* d_out, int out_size, void* d_ws, size_t ws_size,
                              hipStream_t stream) {
    (void)in_sizes; (void)n_in; (void)out_size; (void)ws_size;
    const float* xyz1    = (const float*)d_in[0];
    const float* xyz2    = (const float*)d_in[1];
    const float* points1 = (const float*)d_in[2];
    const float* points2 = (const float*)d_in[3];
    const float* w0      = (const float*)d_in[4];
    // d_in[5] = b0 (cancels under BN), d_in[9] = b1 (cancels)
    const float* g0      = (const float*)d_in[6];
    const float* be0     = (const float*)d_in[7];
    const float* w1      = (const float*)d_in[8];
    const float* g1      = (const float*)d_in[10];
    const float* be1     = (const float*)d_in[11];
    float* out = (float*)d_out;

    char* p = (char*)d_ws;
    float* p2t  = (float*)p;   p += (size_t)BB*SSZ*DD2*4;       // 16 MB
    int*   idx  = (int*)p;     p += (size_t)RTOT*3*4;
    float* wgt  = (float*)p;   p += (size_t)RTOT*3*4;
    __bf16* A1  = (__bf16*)p;  p += (size_t)RTOT*CINC*2;        // 40 MB
    __bf16* y1  = (__bf16*)p;  p += (size_t)RTOT*256*2;         // 32 MB
    __bf16* wb0 = (__bf16*)p;  p += (size_t)256*CINC*2;
    __bf16* wb1 = (__bf16*)p;  p += (size_t)256*256*2;
    float* psum1 = (float*)p;  p += (size_t)(RTOT/128)*256*4;
    float* psq1  = (float*)p;  p += (size_t)(RTOT/128)*256*4;
    float* psum2 = (float*)p;  p += (size_t)(RTOT/128)*256*4;
    float* psq2  = (float*)p;  p += (size_t)(RTOT/128)*256*4;
    float* coef1 = (float*)p;  p += 512*4;
    float* coef2 = (float*)p;  p += 512*4;
    float4* xyz2f4 = (float4*)p; p += (size_t)BB*SSZ*16;        // 256 KB
    float* partS = (float*)p;  p += (size_t)64*256*4;           // 64 KB
    float* partQ = (float*)p;  p += (size_t)64*256*4;           // 64 KB
    __bf16* y2 = A1;   // A1 dead after GEMM1 -> reuse for y2 (32 MB < 40 MB)

    k_prep0       <<<dim3(384),                 dim3(256), 0, stream>>>(xyz2, xyz2f4, w0, w1, wb0, wb1);
    k_transpose_p2<<<dim3(SSZ/32, DD2/32, BB),  dim3(256), 0, stream>>>(points2, p2t);
    k_knn3        <<<dim3(NN/64, BB),           dim3(512), 0, stream>>>(xyz1, xyz2f4, idx, wgt);
    k_points1_to_A1<<<dim3(NN/64, BB),          dim3(256), 0, stream>>>(points1, A1);
    k_interp      <<<dim3(NN/32, BB),           dim3(256), 0, stream>>>(p2t, idx, wgt, A1);
    k_gemm_bn<CINC><<<dim3(RTOT/64),            dim3(256), 0, stream>>>(A1, wb0, y1, psum1, psq1);
    k_bnpart      <<<dim3(64),                  dim3(256), 0, stream>>>(psum1, psq1, partS, partQ);
    k_bnstat      <<<dim3(1),                   dim3(256), 0, stream>>>(partS, partQ, g0, be0, coef1);
    k_gemm2_fused <<<dim3(RTOT/64),             dim3(256), 0, stream>>>(y1, coef1, wb1, y2, psum2, psq2);
    k_bnpart      <<<dim3(64),                  dim3(256), 0, stream>>>(psum2, psq2, partS, partQ);
    k_bnstat      <<<dim3(1),                   dim3(256), 0, stream>>>(partS, partQ, g1, be1, coef2);
    k_final       <<<dim3(NN/64, 256/64, BB),   dim3(256), 0, stream>>>(y2, coef2, out);
}